// Round 8
// baseline (658.195 us; speedup 1.0000x reference)
//
#include <hip/hip_runtime.h>
#include <math.h>

#define HID 128
#define NGAUSS 50
#define TBL 2048
#define TBL2 8192
#define DMAX 8.6605f
#define LDX 136   // fp16 row pitch for per-wave LDS transpose slices

typedef _Float16 h4 __attribute__((ext_vector_type(4)));
typedef _Float16 f16x8 __attribute__((ext_vector_type(8)));
typedef float f32x4 __attribute__((ext_vector_type(4)));

__device__ __forceinline__ float sspf(float x) {
  float ax = fabsf(x);
  return fmaxf(x, 0.0f) + log1pf(expf(-ax)) - 0.69314718055994530942f;
}

// ---- Build W(d) lookup table (fp32, coarse): tab[l][ti][j]
__global__ __launch_bounds__(128) void build_table_k(
    const float* __restrict__ w1, const float* __restrict__ b1,
    const float* __restrict__ w2, const float* __restrict__ b2,
    float* __restrict__ tab) {
  int l = blockIdx.x >> 11;
  int ti = blockIdx.x & (TBL - 1);
  int j = threadIdx.x;
  __shared__ float rbf[NGAUSS];
  __shared__ float v1[HID];
  const float step = DMAX / (float)(TBL - 1);
  float d = ti * step;
  if (j < NGAUSS) {
    const float gstep = 10.0f / 49.0f;
    const float gcoeff = -12.005f;
    float diff = d - j * gstep;
    rbf[j] = expf(gcoeff * diff * diff);
  }
  __syncthreads();
  float s = b1[l * HID + j];
  const float* w1p = w1 + l * NGAUSS * HID + j;
  for (int g = 0; g < NGAUSS; g++) s = fmaf(rbf[g], w1p[g * HID], s);
  v1[j] = sspf(s);
  __syncthreads();
  float s2 = b2[l * HID + j];
  const float* w2p = w2 + l * HID * HID + j;
  for (int k = 0; k < HID; k++) s2 = fmaf(v1[k], w2p[k * HID], s2);
  float C = 0.5f * (cosf(d * 0.3141592653589793f) + 1.0f);
  tab[((size_t)l * TBL + ti) * HID + j] = s2 * C;
}

// ---- upsample coarse fp32 lerp table -> fine fp16 nearest table [l][TBL2][HID]
__global__ __launch_bounds__(256) void upsample_k(
    const float* __restrict__ tab, _Float16* __restrict__ tabh) {
  int idx = blockIdx.x * 256 + threadIdx.x;
  if (idx >= 3 * TBL2 * HID) return;
  int ch = idx & 127;
  int i = (idx >> 7) & (TBL2 - 1);
  int l = idx >> 20;
  float t = (float)i * ((float)(TBL - 1) / (float)(TBL2 - 1));
  int i0 = min((int)t, TBL - 2);
  float f = t - (float)i0;
  const float* base = tab + ((size_t)l * TBL + i0) * HID + ch;
  tabh[idx] = (_Float16)fmaf(f, base[HID] - base[0], base[0]);
}

// ---- transpose+convert 9 128x128 weights + out1_w (128x64) to fp16 Wt[n][k]
__global__ __launch_bounds__(256) void wtrans10_k(
    const float* __restrict__ lin1, const float* __restrict__ lin2,
    const float* __restrict__ intw, const float* __restrict__ out1w,
    _Float16* __restrict__ out) {
  int b = blockIdx.x;
  __shared__ _Float16 tile[128 * 130];
  int t = threadIdx.x;
  if (b < 9) {
    const float* src = (b < 3 ? lin1 : (b < 6 ? lin2 : intw)) + (size_t)(b % 3) * HID * HID;
    _Float16* dst = out + (size_t)b * HID * HID;
    for (int i = t; i < HID * HID; i += 256) tile[(i >> 7) * 130 + (i & 127)] = (_Float16)src[i];
    __syncthreads();
    for (int i = t; i < HID * HID; i += 256) dst[i] = tile[(i & 127) * 130 + (i >> 7)];
  } else {
    _Float16* dst = out + (size_t)9 * HID * HID;
    for (int i = t; i < 128 * 64; i += 256) tile[(i >> 6) * 66 + (i & 63)] = (_Float16)out1w[i];
    __syncthreads();
    for (int i = t; i < 64 * 128; i += 256) dst[i] = tile[(i & 127) * 66 + (i >> 7)];
  }
}

// ---- bucket (col>>6) histogram, LDS-aggregated
__global__ __launch_bounds__(256) void bcount_k(
    const int* __restrict__ col, int* __restrict__ bcount, int E, int nbuck) {
  __shared__ int hist[1024];
  int t = threadIdx.x;
  int e0 = blockIdx.x * 2048;
  for (int j = t; j < nbuck; j += 256) hist[j] = 0;
  __syncthreads();
#pragma unroll
  for (int u = 0; u < 8; u++) {
    int e = e0 + u * 256 + t;
    if (e < E) atomicAdd(&hist[col[e] >> 6], 1);
  }
  __syncthreads();
  for (int j = t; j < nbuck; j += 256)
    if (hist[j]) atomicAdd(&bcount[j], hist[j]);
}

// ---- exclusive scan of bucket counts (single block)
__global__ __launch_bounds__(256) void bucket_scan_k(
    const int* __restrict__ bcount, int* __restrict__ bstart,
    int* __restrict__ bcur, int nbuck, int* __restrict__ starts, int N) {
  __shared__ int sh[256];
  int t = threadIdx.x;
  int chunk = (nbuck + 255) / 256;
  int b0 = t * chunk;
  int c[8];
  int s = 0;
  for (int j = 0; j < chunk; j++) {
    int idx = b0 + j;
    int v = (idx < nbuck) ? bcount[idx] : 0;
    c[j] = v;
    s += v;
  }
  sh[t] = s;
  __syncthreads();
  for (int o = 1; o < 256; o <<= 1) {
    int v = (t >= o) ? sh[t - o] : 0;
    __syncthreads();
    sh[t] += v;
    __syncthreads();
  }
  int p = (t == 0) ? 0 : sh[t - 1];
  for (int j = 0; j < chunk; j++) {
    int idx = b0 + j;
    if (idx < nbuck) {
      bstart[idx] = p;
      bcur[idx] = p;
      p += c[j];
    }
  }
  if (t == 255) {
    bstart[nbuck] = p;
    starts[N] = p;
  }
}

// ---- level-1 scatter: distance inline, key64 into 64-atom bucket chunks
__global__ __launch_bounds__(256) void scatterA_k(
    const int* __restrict__ row, const int* __restrict__ col,
    const float* __restrict__ pos, int* __restrict__ bcur,
    unsigned long long* __restrict__ tmp, int E, int nbuck) {
  __shared__ int hist[1024];
  __shared__ int base[1024];
  int t = threadIdx.x;
  int e0 = blockIdx.x * 2048;
  for (int j = t; j < nbuck; j += 256) hist[j] = 0;
  __syncthreads();
  int bkt[8];
  int rnk[8];
  unsigned long long key[8];
#pragma unroll
  for (int u = 0; u < 8; u++) {
    int e = e0 + u * 256 + t;
    bkt[u] = -1;
    if (e < E) {
      int r = row[e], c = col[e];
      float dx = pos[r * 3 + 0] - pos[c * 3 + 0];
      float dy = pos[r * 3 + 1] - pos[c * 3 + 1];
      float dz = pos[r * 3 + 2] - pos[c * 3 + 2];
      float d = sqrtf(dx * dx + dy * dy + dz * dz);
      const float inv2 = (float)(TBL2 - 1) / DMAX;
      int q = min((int)(d * inv2 + 0.5f), TBL2 - 1);
      unsigned int pay = ((unsigned int)r << 13) | (unsigned int)q;
      key[u] = ((unsigned long long)pay << 6) | (unsigned long long)(c & 63);
      bkt[u] = c >> 6;
      rnk[u] = atomicAdd(&hist[bkt[u]], 1);
    }
  }
  __syncthreads();
  for (int j = t; j < nbuck; j += 256)
    base[j] = hist[j] ? atomicAdd(&bcur[j], hist[j]) : 0;
  __syncthreads();
#pragma unroll
  for (int u = 0; u < 8; u++)
    if (bkt[u] >= 0) tmp[(size_t)base[bkt[u]] + rnk[u]] = key[u];
}

// ---- level-2: per-bucket per-atom counts -> starts, then local scatter
__global__ __launch_bounds__(256) void scatterB_k(
    const unsigned long long* __restrict__ tmp, const int* __restrict__ bstart,
    int* __restrict__ starts, unsigned int* __restrict__ payload, int N) {
  int j = blockIdx.x;
  int t = threadIdx.x;
  __shared__ int cnt[64];
  __shared__ int cur[64];
  int rs = bstart[j], re = bstart[j + 1];
  if (t < 64) cnt[t] = 0;
  __syncthreads();
  for (int e = rs + t; e < re; e += 256)
    atomicAdd(&cnt[(int)(tmp[e] & 63)], 1);
  __syncthreads();
  if (t < 64) {
    int mine = cnt[t];
    int v = mine;
    for (int o = 1; o < 64; o <<= 1) {
      int u = __shfl_up(v, o, 64);
      if (t >= o) v += u;
    }
    int excl = v - mine;
    int c = j * 64 + t;
    if (c < N) starts[c] = rs + excl;
    cur[t] = rs + excl;
  }
  __syncthreads();
  for (int e = rs + t; e < re; e += 256) {
    unsigned long long k = tmp[e];
    int p = atomicAdd(&cur[(int)(k & 63)], 1);
    payload[p] = (unsigned int)(k >> 6);
  }
}

// ---- layer-0: h = emb[z], x16 = h @ W1_0.  Barrier-free, no LDS.
__global__ __launch_bounds__(256) void lin1_emb_k(
    const int* __restrict__ z, const float* __restrict__ emb,
    const _Float16* __restrict__ W1t, float* __restrict__ h,
    _Float16* __restrict__ x16, int N) {
  int t = threadIdx.x;
  int lane = t & 63, w = t >> 6;
  int mrow = lane & 15, quad = lane >> 4;
  int a0 = blockIdx.x * 64;
  int am = a0 + w * 16 + mrow;
  int amc = min(am, N - 1);
  int zz = z[amc];
  const float* er = emb + (size_t)zz * HID;
  f16x8 af[4];
#pragma unroll
  for (int kk = 0; kk < 4; kk++) {
    float4 e0 = *(const float4*)(er + kk * 32 + quad * 8);
    float4 e1 = *(const float4*)(er + kk * 32 + quad * 8 + 4);
    if (am < N) {
      *(float4*)(h + (size_t)am * HID + kk * 32 + quad * 8) = e0;
      *(float4*)(h + (size_t)am * HID + kk * 32 + quad * 8 + 4) = e1;
    }
    f16x8 a8;
    a8[0] = (_Float16)e0.x; a8[1] = (_Float16)e0.y;
    a8[2] = (_Float16)e0.z; a8[3] = (_Float16)e0.w;
    a8[4] = (_Float16)e1.x; a8[5] = (_Float16)e1.y;
    a8[6] = (_Float16)e1.z; a8[7] = (_Float16)e1.w;
    af[kk] = a8;
  }
  f32x4 zero = {0.f, 0.f, 0.f, 0.f};
  f32x4 acc[8];
#pragma unroll
  for (int i = 0; i < 8; i++) acc[i] = zero;
#pragma unroll
  for (int kk = 0; kk < 4; kk++) {
    f16x8 bf[8];
#pragma unroll
    for (int nt = 0; nt < 8; nt++)
      bf[nt] = *(const f16x8*)(W1t + (size_t)(nt * 16 + mrow) * HID + kk * 32 + quad * 8);
#pragma unroll
    for (int nt = 0; nt < 8; nt++)
      acc[nt] = __builtin_amdgcn_mfma_f32_16x16x32_f16(af[kk], bf[nt], acc[nt], 0, 0, 0);
  }
#pragma unroll
  for (int nt = 0; nt < 8; nt++) {
    int colv = nt * 16 + mrow;
#pragma unroll
    for (int r = 0; r < 4; r++) {
      int a = a0 + w * 16 + quad * 4 + r;
      if (a < N) x16[(size_t)a * HID + colv] = (_Float16)acc[nt][r];
    }
  }
}

// ---- mid layers: h' = h + ssp(agg@W2+b2)@W3+b3 (store h), x16 = h'@W1next.
// Barrier-free: B-frags from global (L2-hot), per-wave LDS transpose slices.
__global__ __launch_bounds__(256) void fused_mid_k(
    const _Float16* __restrict__ agg16, const _Float16* __restrict__ W2t,
    const float* __restrict__ b2, const _Float16* __restrict__ W3t,
    const float* __restrict__ b3, float* __restrict__ h,
    const _Float16* __restrict__ W1nt, _Float16* __restrict__ x16, int N) {
  __shared__ __align__(16) _Float16 Xs[64 * LDX];
  int t = threadIdx.x;
  int lane = t & 63, w = t >> 6;
  int mrow = lane & 15, quad = lane >> 4;
  int a0 = blockIdx.x * 64;
  int am = min(a0 + w * 16 + mrow, N - 1);
  f16x8 af[4];
  const _Float16* arow = agg16 + (size_t)am * HID;
#pragma unroll
  for (int kk = 0; kk < 4; kk++)
    af[kk] = *(const f16x8*)(arow + kk * 32 + quad * 8);
  f32x4 zero = {0.f, 0.f, 0.f, 0.f};
  f32x4 acc[8];
#pragma unroll
  for (int i = 0; i < 8; i++) acc[i] = zero;
#pragma unroll
  for (int kk = 0; kk < 4; kk++) {
    f16x8 bf[8];
#pragma unroll
    for (int nt = 0; nt < 8; nt++)
      bf[nt] = *(const f16x8*)(W2t + (size_t)(nt * 16 + mrow) * HID + kk * 32 + quad * 8);
#pragma unroll
    for (int nt = 0; nt < 8; nt++)
      acc[nt] = __builtin_amdgcn_mfma_f32_16x16x32_f16(af[kk], bf[nt], acc[nt], 0, 0, 0);
  }
  // epilogue1: ssp(+b2) -> per-wave LDS slice (C->A transpose), no barrier
#pragma unroll
  for (int nt = 0; nt < 8; nt++) {
    float bb = b2[nt * 16 + mrow];
#pragma unroll
    for (int r = 0; r < 4; r++)
      Xs[(w * 16 + quad * 4 + r) * LDX + nt * 16 + mrow] = (_Float16)sspf(acc[nt][r] + bb);
  }
#pragma unroll
  for (int kk = 0; kk < 4; kk++)
    af[kk] = *(const f16x8*)&Xs[(w * 16 + mrow) * LDX + kk * 32 + quad * 8];
#pragma unroll
  for (int i = 0; i < 8; i++) acc[i] = zero;
#pragma unroll
  for (int kk = 0; kk < 4; kk++) {
    f16x8 bf[8];
#pragma unroll
    for (int nt = 0; nt < 8; nt++)
      bf[nt] = *(const f16x8*)(W3t + (size_t)(nt * 16 + mrow) * HID + kk * 32 + quad * 8);
#pragma unroll
    for (int nt = 0; nt < 8; nt++)
      acc[nt] = __builtin_amdgcn_mfma_f32_16x16x32_f16(af[kk], bf[nt], acc[nt], 0, 0, 0);
  }
  // residual: h' = h + acc + b3 (C-layout dword RMW), stage h' fp16 to LDS slice
#pragma unroll
  for (int nt = 0; nt < 8; nt++) {
    int colv = nt * 16 + mrow;
    float bb = b3[colv];
#pragma unroll
    for (int r = 0; r < 4; r++) {
      int a = a0 + w * 16 + quad * 4 + r;
      float v = acc[nt][r] + bb;
      if (a < N) {
        float* hp = h + (size_t)a * HID + colv;
        v += *hp;
        *hp = v;
      }
      Xs[(w * 16 + quad * 4 + r) * LDX + colv] = (_Float16)v;
    }
  }
#pragma unroll
  for (int kk = 0; kk < 4; kk++)
    af[kk] = *(const f16x8*)&Xs[(w * 16 + mrow) * LDX + kk * 32 + quad * 8];
#pragma unroll
  for (int i = 0; i < 8; i++) acc[i] = zero;
#pragma unroll
  for (int kk = 0; kk < 4; kk++) {
    f16x8 bf[8];
#pragma unroll
    for (int nt = 0; nt < 8; nt++)
      bf[nt] = *(const f16x8*)(W1nt + (size_t)(nt * 16 + mrow) * HID + kk * 32 + quad * 8);
#pragma unroll
    for (int nt = 0; nt < 8; nt++)
      acc[nt] = __builtin_amdgcn_mfma_f32_16x16x32_f16(af[kk], bf[nt], acc[nt], 0, 0, 0);
  }
#pragma unroll
  for (int nt = 0; nt < 8; nt++) {
    int colv = nt * 16 + mrow;
#pragma unroll
    for (int r = 0; r < 4; r++) {
      int a = a0 + w * 16 + quad * 4 + r;
      if (a < N) x16[(size_t)a * HID + colv] = (_Float16)acc[nt][r];
    }
  }
}

// ---- last layer: h'=h+... (not stored) -> ssp(h'@o1w+o1b).o2w -> atomic out[batch]
__global__ __launch_bounds__(256) void fused_last_k(
    const _Float16* __restrict__ agg16, const _Float16* __restrict__ W2t,
    const float* __restrict__ b2, const _Float16* __restrict__ W3t,
    const float* __restrict__ b3, const float* __restrict__ h,
    const _Float16* __restrict__ Wo1t, const float* __restrict__ o1b,
    const float* __restrict__ o2w, const float* __restrict__ o2b,
    const int* __restrict__ batch, float* __restrict__ out, int N) {
  __shared__ __align__(16) _Float16 Xs[64 * LDX];
  int t = threadIdx.x;
  int lane = t & 63, w = t >> 6;
  int mrow = lane & 15, quad = lane >> 4;
  int a0 = blockIdx.x * 64;
  int am = min(a0 + w * 16 + mrow, N - 1);
  f16x8 af[4];
  const _Float16* arow = agg16 + (size_t)am * HID;
#pragma unroll
  for (int kk = 0; kk < 4; kk++)
    af[kk] = *(const f16x8*)(arow + kk * 32 + quad * 8);
  f32x4 zero = {0.f, 0.f, 0.f, 0.f};
  f32x4 acc[8];
#pragma unroll
  for (int i = 0; i < 8; i++) acc[i] = zero;
#pragma unroll
  for (int kk = 0; kk < 4; kk++) {
    f16x8 bf[8];
#pragma unroll
    for (int nt = 0; nt < 8; nt++)
      bf[nt] = *(const f16x8*)(W2t + (size_t)(nt * 16 + mrow) * HID + kk * 32 + quad * 8);
#pragma unroll
    for (int nt = 0; nt < 8; nt++)
      acc[nt] = __builtin_amdgcn_mfma_f32_16x16x32_f16(af[kk], bf[nt], acc[nt], 0, 0, 0);
  }
#pragma unroll
  for (int nt = 0; nt < 8; nt++) {
    float bb = b2[nt * 16 + mrow];
#pragma unroll
    for (int r = 0; r < 4; r++)
      Xs[(w * 16 + quad * 4 + r) * LDX + nt * 16 + mrow] = (_Float16)sspf(acc[nt][r] + bb);
  }
#pragma unroll
  for (int kk = 0; kk < 4; kk++)
    af[kk] = *(const f16x8*)&Xs[(w * 16 + mrow) * LDX + kk * 32 + quad * 8];
#pragma unroll
  for (int i = 0; i < 8; i++) acc[i] = zero;
#pragma unroll
  for (int kk = 0; kk < 4; kk++) {
    f16x8 bf[8];
#pragma unroll
    for (int nt = 0; nt < 8; nt++)
      bf[nt] = *(const f16x8*)(W3t + (size_t)(nt * 16 + mrow) * HID + kk * 32 + quad * 8);
#pragma unroll
    for (int nt = 0; nt < 8; nt++)
      acc[nt] = __builtin_amdgcn_mfma_f32_16x16x32_f16(af[kk], bf[nt], acc[nt], 0, 0, 0);
  }
#pragma unroll
  for (int nt = 0; nt < 8; nt++) {
    int colv = nt * 16 + mrow;
    float bb = b3[colv];
#pragma unroll
    for (int r = 0; r < 4; r++) {
      int a = a0 + w * 16 + quad * 4 + r;
      float v = acc[nt][r] + bb;
      if (a < N) v += h[(size_t)a * HID + colv];
      Xs[(w * 16 + quad * 4 + r) * LDX + colv] = (_Float16)v;
    }
  }
#pragma unroll
  for (int kk = 0; kk < 4; kk++)
    af[kk] = *(const f16x8*)&Xs[(w * 16 + mrow) * LDX + kk * 32 + quad * 8];
#pragma unroll
  for (int i = 0; i < 4; i++) acc[i] = zero;
#pragma unroll
  for (int kk = 0; kk < 4; kk++) {
    f16x8 bf[4];
#pragma unroll
    for (int nt = 0; nt < 4; nt++)
      bf[nt] = *(const f16x8*)(Wo1t + (size_t)(nt * 16 + mrow) * HID + kk * 32 + quad * 8);
#pragma unroll
    for (int nt = 0; nt < 4; nt++)
      acc[nt] = __builtin_amdgcn_mfma_f32_16x16x32_f16(af[kk], bf[nt], acc[nt], 0, 0, 0);
  }
  float o2b0 = o2b[0];
  float ss[4] = {0.f, 0.f, 0.f, 0.f};
#pragma unroll
  for (int nt = 0; nt < 4; nt++) {
    float bb = o1b[nt * 16 + mrow];
    float ww = o2w[nt * 16 + mrow];
#pragma unroll
    for (int r = 0; r < 4; r++) ss[r] += sspf(acc[nt][r] + bb) * ww;
  }
#pragma unroll
  for (int r = 0; r < 4; r++) {
    ss[r] += __shfl_xor(ss[r], 1);
    ss[r] += __shfl_xor(ss[r], 2);
    ss[r] += __shfl_xor(ss[r], 4);
    ss[r] += __shfl_xor(ss[r], 8);
    int a = a0 + w * 16 + quad * 4 + r;
    if (mrow == 0 && a < N) atomicAdd(&out[batch[a]], ss[r] + o2b0);
  }
}

// ---- agg16[a] = (fp16) sum_{e: col=a} x16[row_e] * tabh[tq_e]
__global__ __launch_bounds__(256) void aggregate_k(
    const int* __restrict__ starts, const unsigned int* __restrict__ payload,
    const _Float16* __restrict__ x16, const _Float16* __restrict__ tabh,
    _Float16* __restrict__ agg16, int N) {
  int a = blockIdx.x * 4 + (threadIdx.x >> 6);
  if (a >= N) return;
  int lane = threadIdx.x & 63;
  int half = lane >> 5;
  int sl = lane & 31;
  int s = starts[a], e_end = starts[a + 1];
  float4 acc0 = make_float4(0.f, 0.f, 0.f, 0.f);
  float4 acc1 = make_float4(0.f, 0.f, 0.f, 0.f);
  auto do_edge = [&](unsigned int p, float4& acc) {
    int tq = (int)(p & 8191u);
    int r = (int)(p >> 13);
    h4 tw = *(const h4*)&tabh[(size_t)tq * HID + sl * 4];
    h4 xr = *(const h4*)&x16[(size_t)r * HID + sl * 4];
    acc.x = fmaf((float)xr.x, (float)tw.x, acc.x);
    acc.y = fmaf((float)xr.y, (float)tw.y, acc.y);
    acc.z = fmaf((float)xr.z, (float)tw.z, acc.z);
    acc.w = fmaf((float)xr.w, (float)tw.w, acc.w);
  };
  int i = s;
  for (; i + 8 <= e_end; i += 8) {
    unsigned int p0 = payload[i + half];
    unsigned int p1 = payload[i + 2 + half];
    unsigned int p2 = payload[i + 4 + half];
    unsigned int p3 = payload[i + 6 + half];
    do_edge(p0, acc0);
    do_edge(p1, acc1);
    do_edge(p2, acc0);
    do_edge(p3, acc1);
  }
  for (; i < e_end; i += 2) {
    int e = i + half;
    if (e < e_end) do_edge(payload[e], acc0);
  }
  acc0.x += acc1.x; acc0.y += acc1.y; acc0.z += acc1.z; acc0.w += acc1.w;
  acc0.x += __shfl_xor(acc0.x, 32);
  acc0.y += __shfl_xor(acc0.y, 32);
  acc0.z += __shfl_xor(acc0.z, 32);
  acc0.w += __shfl_xor(acc0.w, 32);
  if (half == 0) {
    h4 o;
    o.x = (_Float16)acc0.x; o.y = (_Float16)acc0.y;
    o.z = (_Float16)acc0.z; o.w = (_Float16)acc0.w;
    *(h4*)&agg16[(size_t)a * HID + sl * 4] = o;
  }
}

extern "C" void kernel_launch(void* const* d_in, const int* in_sizes, int n_in,
                              void* d_out, int out_size, void* d_ws, size_t ws_size,
                              hipStream_t stream) {
  const int* z = (const int*)d_in[0];
  const float* pos = (const float*)d_in[1];
  const int* batch = (const int*)d_in[2];
  const int* eidx = (const int*)d_in[3];
  const float* emb = (const float*)d_in[4];
  const float* mlp1_w = (const float*)d_in[5];
  const float* mlp1_b = (const float*)d_in[6];
  const float* mlp2_w = (const float*)d_in[7];
  const float* mlp2_b = (const float*)d_in[8];
  const float* lin1_w = (const float*)d_in[9];
  const float* lin2_w = (const float*)d_in[10];
  const float* lin2_b = (const float*)d_in[11];
  const float* int_w = (const float*)d_in[12];
  const float* int_b = (const float*)d_in[13];
  const float* out1_w = (const float*)d_in[14];
  const float* out1_b = (const float*)d_in[15];
  const float* out2_w = (const float*)d_in[16];
  const float* out2_b = (const float*)d_in[17];
  float* out = (float*)d_out;

  const int N = in_sizes[0];
  const int E = in_sizes[3] / 2;
  const int* row = eidx;
  const int* col = eidx + E;
  const int nbuck = (N + 63) / 64;

  char* ws = (char*)d_ws;
  size_t off = 0;
  auto alloc = [&](size_t bytes) -> void* {
    void* p = ws + off;
    off = (off + bytes + 255) & ~(size_t)255;
    return p;
  };
  float* h = (float*)alloc((size_t)N * HID * 4);
  _Float16* x16 = (_Float16*)alloc((size_t)N * HID * 2);
  size_t agg_bytes = (size_t)N * HID * 2;
  size_t tmp_bytes = (size_t)E * 8 + 16;
  void* agg_union = alloc(agg_bytes > tmp_bytes ? agg_bytes : tmp_bytes);
  _Float16* agg16 = (_Float16*)agg_union;
  unsigned long long* tmp = (unsigned long long*)agg_union;
  unsigned int* payload = (unsigned int*)alloc((size_t)E * 4 + 16);
  int* starts = (int*)alloc((size_t)(N + 1) * 4);
  int* bcount = (int*)alloc((size_t)nbuck * 4);
  int* bstart = (int*)alloc((size_t)(nbuck + 1) * 4);
  int* bcur = (int*)alloc((size_t)nbuck * 4);
  float* tab = (float*)alloc((size_t)3 * TBL * HID * 4);
  _Float16* tabh = (_Float16*)alloc((size_t)3 * TBL2 * HID * 2);
  _Float16* Wt10 = (_Float16*)alloc((size_t)10 * HID * HID * 2);
  (void)ws_size;

  hipMemsetAsync(bcount, 0, (size_t)nbuck * 4, stream);
  hipMemsetAsync(out, 0, (size_t)out_size * 4, stream);

  build_table_k<<<3 * TBL, 128, 0, stream>>>(mlp1_w, mlp1_b, mlp2_w, mlp2_b, tab);
  upsample_k<<<(3 * TBL2 * HID + 255) / 256, 256, 0, stream>>>(tab, tabh);
  wtrans10_k<<<10, 256, 0, stream>>>(lin1_w, lin2_w, int_w, out1_w, Wt10);
  bcount_k<<<(E + 2047) / 2048, 256, 0, stream>>>(col, bcount, E, nbuck);
  bucket_scan_k<<<1, 256, 0, stream>>>(bcount, bstart, bcur, nbuck, starts, N);
  scatterA_k<<<(E + 2047) / 2048, 256, 0, stream>>>(row, col, pos, bcur, tmp, E, nbuck);
  scatterB_k<<<nbuck, 256, 0, stream>>>(tmp, bstart, starts, payload, N);

  int gemm_grid = (N + 63) / 64;
  lin1_emb_k<<<gemm_grid, 256, 0, stream>>>(z, emb, Wt10, h, x16, N);
  for (int l = 0; l < 2; l++) {
    aggregate_k<<<(N + 3) / 4, 256, 0, stream>>>(starts, payload, x16,
                                                 tabh + (size_t)l * TBL2 * HID, agg16, N);
    fused_mid_k<<<gemm_grid, 256, 0, stream>>>(
        agg16, Wt10 + (size_t)(3 + l) * HID * HID, lin2_b + (size_t)l * HID,
        Wt10 + (size_t)(6 + l) * HID * HID, int_b + (size_t)l * HID, h,
        Wt10 + (size_t)(l + 1) * HID * HID, x16, N);
  }
  aggregate_k<<<(N + 3) / 4, 256, 0, stream>>>(starts, payload, x16,
                                               tabh + (size_t)2 * TBL2 * HID, agg16, N);
  fused_last_k<<<gemm_grid, 256, 0, stream>>>(
      agg16, Wt10 + (size_t)5 * HID * HID, lin2_b + (size_t)2 * HID,
      Wt10 + (size_t)8 * HID * HID, int_b + (size_t)2 * HID, h,
      Wt10 + (size_t)9 * HID * HID, out1_b, out2_w, out2_b, batch, out, N);
}

// Round 9
// 617.454 us; speedup vs baseline: 1.0660x; 1.0660x over previous
//
#include <hip/hip_runtime.h>
#include <math.h>

#define HID 128
#define NGAUSS 50
#define TBL 2048
#define TBL2 8192
#define DMAX 8.6605f
#define LDX 136   // fp16 row pitch for LDS tiles (272 B, 16B-aligned)

typedef _Float16 h4 __attribute__((ext_vector_type(4)));
typedef _Float16 f16x8 __attribute__((ext_vector_type(8)));
typedef float f32x4 __attribute__((ext_vector_type(4)));

__device__ __forceinline__ float sspf(float x) {
  float ax = fabsf(x);
  return fmaxf(x, 0.0f) + log1pf(expf(-ax)) - 0.69314718055994530942f;
}

// ---- Build W(d) lookup table (fp32, coarse): tab[l][ti][j]
__global__ __launch_bounds__(128) void build_table_k(
    const float* __restrict__ w1, const float* __restrict__ b1,
    const float* __restrict__ w2, const float* __restrict__ b2,
    float* __restrict__ tab) {
  int l = blockIdx.x >> 11;
  int ti = blockIdx.x & (TBL - 1);
  int j = threadIdx.x;
  __shared__ float rbf[NGAUSS];
  __shared__ float v1[HID];
  const float step = DMAX / (float)(TBL - 1);
  float d = ti * step;
  if (j < NGAUSS) {
    const float gstep = 10.0f / 49.0f;
    const float gcoeff = -12.005f;
    float diff = d - j * gstep;
    rbf[j] = expf(gcoeff * diff * diff);
  }
  __syncthreads();
  float s = b1[l * HID + j];
  const float* w1p = w1 + l * NGAUSS * HID + j;
  for (int g = 0; g < NGAUSS; g++) s = fmaf(rbf[g], w1p[g * HID], s);
  v1[j] = sspf(s);
  __syncthreads();
  float s2 = b2[l * HID + j];
  const float* w2p = w2 + l * HID * HID + j;
  for (int k = 0; k < HID; k++) s2 = fmaf(v1[k], w2p[k * HID], s2);
  float C = 0.5f * (cosf(d * 0.3141592653589793f) + 1.0f);
  tab[((size_t)l * TBL + ti) * HID + j] = s2 * C;
}

// ---- upsample coarse fp32 lerp table -> fine fp16 nearest table [l][TBL2][HID]
__global__ __launch_bounds__(256) void upsample_k(
    const float* __restrict__ tab, _Float16* __restrict__ tabh) {
  int idx = blockIdx.x * 256 + threadIdx.x;
  if (idx >= 3 * TBL2 * HID) return;
  int ch = idx & 127;
  int i = (idx >> 7) & (TBL2 - 1);
  int l = idx >> 20;
  float t = (float)i * ((float)(TBL - 1) / (float)(TBL2 - 1));
  int i0 = min((int)t, TBL - 2);
  float f = t - (float)i0;
  const float* base = tab + ((size_t)l * TBL + i0) * HID + ch;
  tabh[idx] = (_Float16)fmaf(f, base[HID] - base[0], base[0]);
}

// ---- transpose+convert 9 128x128 weights + out1_w (128x64) to fp16 Wt[n][k]
__global__ __launch_bounds__(256) void wtrans10_k(
    const float* __restrict__ lin1, const float* __restrict__ lin2,
    const float* __restrict__ intw, const float* __restrict__ out1w,
    _Float16* __restrict__ out) {
  int b = blockIdx.x;
  __shared__ _Float16 tile[128 * 130];
  int t = threadIdx.x;
  if (b < 9) {
    const float* src = (b < 3 ? lin1 : (b < 6 ? lin2 : intw)) + (size_t)(b % 3) * HID * HID;
    _Float16* dst = out + (size_t)b * HID * HID;
    for (int i = t; i < HID * HID; i += 256) tile[(i >> 7) * 130 + (i & 127)] = (_Float16)src[i];
    __syncthreads();
    for (int i = t; i < HID * HID; i += 256) dst[i] = tile[(i & 127) * 130 + (i >> 7)];
  } else {
    _Float16* dst = out + (size_t)9 * HID * HID;
    for (int i = t; i < 128 * 64; i += 256) tile[(i >> 6) * 66 + (i & 63)] = (_Float16)out1w[i];
    __syncthreads();
    for (int i = t; i < 64 * 128; i += 256) dst[i] = tile[(i & 127) * 66 + (i >> 7)];
  }
}

// ---- bucket (col>>6) histogram, LDS-aggregated
__global__ __launch_bounds__(256) void bcount_k(
    const int* __restrict__ col, int* __restrict__ bcount, int E, int nbuck) {
  __shared__ int hist[1024];
  int t = threadIdx.x;
  int e0 = blockIdx.x * 2048;
  for (int j = t; j < nbuck; j += 256) hist[j] = 0;
  __syncthreads();
#pragma unroll
  for (int u = 0; u < 8; u++) {
    int e = e0 + u * 256 + t;
    if (e < E) atomicAdd(&hist[col[e] >> 6], 1);
  }
  __syncthreads();
  for (int j = t; j < nbuck; j += 256)
    if (hist[j]) atomicAdd(&bcount[j], hist[j]);
}

// ---- exclusive scan of bucket counts (single block)
__global__ __launch_bounds__(256) void bucket_scan_k(
    const int* __restrict__ bcount, int* __restrict__ bstart,
    int* __restrict__ bcur, int nbuck, int* __restrict__ starts, int N) {
  __shared__ int sh[256];
  int t = threadIdx.x;
  int chunk = (nbuck + 255) / 256;
  int b0 = t * chunk;
  int c[8];
  int s = 0;
  for (int j = 0; j < chunk; j++) {
    int idx = b0 + j;
    int v = (idx < nbuck) ? bcount[idx] : 0;
    c[j] = v;
    s += v;
  }
  sh[t] = s;
  __syncthreads();
  for (int o = 1; o < 256; o <<= 1) {
    int v = (t >= o) ? sh[t - o] : 0;
    __syncthreads();
    sh[t] += v;
    __syncthreads();
  }
  int p = (t == 0) ? 0 : sh[t - 1];
  for (int j = 0; j < chunk; j++) {
    int idx = b0 + j;
    if (idx < nbuck) {
      bstart[idx] = p;
      bcur[idx] = p;
      p += c[j];
    }
  }
  if (t == 255) {
    bstart[nbuck] = p;
    starts[N] = p;
  }
}

// ---- level-1 scatter: distance inline, key64 into 64-atom bucket chunks
__global__ __launch_bounds__(256) void scatterA_k(
    const int* __restrict__ row, const int* __restrict__ col,
    const float* __restrict__ pos, int* __restrict__ bcur,
    unsigned long long* __restrict__ tmp, int E, int nbuck) {
  __shared__ int hist[1024];
  __shared__ int base[1024];
  int t = threadIdx.x;
  int e0 = blockIdx.x * 2048;
  for (int j = t; j < nbuck; j += 256) hist[j] = 0;
  __syncthreads();
  int bkt[8];
  int rnk[8];
  unsigned long long key[8];
#pragma unroll
  for (int u = 0; u < 8; u++) {
    int e = e0 + u * 256 + t;
    bkt[u] = -1;
    if (e < E) {
      int r = row[e], c = col[e];
      float dx = pos[r * 3 + 0] - pos[c * 3 + 0];
      float dy = pos[r * 3 + 1] - pos[c * 3 + 1];
      float dz = pos[r * 3 + 2] - pos[c * 3 + 2];
      float d = sqrtf(dx * dx + dy * dy + dz * dz);
      const float inv2 = (float)(TBL2 - 1) / DMAX;
      int q = min((int)(d * inv2 + 0.5f), TBL2 - 1);
      unsigned int pay = ((unsigned int)r << 13) | (unsigned int)q;
      key[u] = ((unsigned long long)pay << 6) | (unsigned long long)(c & 63);
      bkt[u] = c >> 6;
      rnk[u] = atomicAdd(&hist[bkt[u]], 1);
    }
  }
  __syncthreads();
  for (int j = t; j < nbuck; j += 256)
    base[j] = hist[j] ? atomicAdd(&bcur[j], hist[j]) : 0;
  __syncthreads();
#pragma unroll
  for (int u = 0; u < 8; u++)
    if (bkt[u] >= 0) tmp[(size_t)base[bkt[u]] + rnk[u]] = key[u];
}

// ---- level-2: per-bucket per-atom counts -> starts, then local scatter
__global__ __launch_bounds__(256) void scatterB_k(
    const unsigned long long* __restrict__ tmp, const int* __restrict__ bstart,
    int* __restrict__ starts, unsigned int* __restrict__ payload, int N) {
  int j = blockIdx.x;
  int t = threadIdx.x;
  __shared__ int cnt[64];
  __shared__ int cur[64];
  int rs = bstart[j], re = bstart[j + 1];
  if (t < 64) cnt[t] = 0;
  __syncthreads();
  for (int e = rs + t; e < re; e += 256)
    atomicAdd(&cnt[(int)(tmp[e] & 63)], 1);
  __syncthreads();
  if (t < 64) {
    int mine = cnt[t];
    int v = mine;
    for (int o = 1; o < 64; o <<= 1) {
      int u = __shfl_up(v, o, 64);
      if (t >= o) v += u;
    }
    int excl = v - mine;
    int c = j * 64 + t;
    if (c < N) starts[c] = rs + excl;
    cur[t] = rs + excl;
  }
  __syncthreads();
  for (int e = rs + t; e < re; e += 256) {
    unsigned long long k = tmp[e];
    int p = atomicAdd(&cur[(int)(k & 63)], 1);
    payload[p] = (unsigned int)(k >> 6);
  }
}

// 32-atom col-split GEMM block geometry:
//   4 waves: g = w&1 (atom group of 16), c = w>>1 (column half of 64)
//   per-wave per-stage: 4 kk x 4 nt = 16 MFMA

// ---- layer-0: h = emb[z], x16 = h @ W1_0
__global__ __launch_bounds__(256) void lin1_emb_k(
    const int* __restrict__ z, const float* __restrict__ emb,
    const _Float16* __restrict__ W1t, float* __restrict__ h,
    _Float16* __restrict__ x16, int N) {
  __shared__ __align__(16) _Float16 Xs[32 * LDX];
  __shared__ __align__(16) _Float16 Ys[32 * LDX];
  __shared__ int zi[32];
  int t = threadIdx.x;
  int lane = t & 63, w = t >> 6;
  int g = w & 1, c = w >> 1;
  int mrow = lane & 15, quad = lane >> 4;
  int a0 = blockIdx.x * 32;
  if (t < 32) zi[t] = (a0 + t < N) ? z[a0 + t] : 0;
  __syncthreads();
#pragma unroll
  for (int p = 0; p < 4; p++) {
    int id = t + p * 256;          // 1024 float4 chunks (32 rows x 32)
    int a = id >> 5, kg = id & 31;
    float4 v = ((const float4*)emb)[(size_t)zi[a] * 32 + kg];
    if (a0 + a < N) ((float4*)h)[(size_t)(a0 + a) * 32 + kg] = v;
    h4 o;
    o.x = (_Float16)v.x; o.y = (_Float16)v.y;
    o.z = (_Float16)v.z; o.w = (_Float16)v.w;
    *(h4*)&Xs[a * LDX + kg * 4] = o;
  }
  __syncthreads();
  f16x8 af[4];
#pragma unroll
  for (int kk = 0; kk < 4; kk++)
    af[kk] = *(const f16x8*)&Xs[(g * 16 + mrow) * LDX + kk * 32 + quad * 8];
  f32x4 zero = {0.f, 0.f, 0.f, 0.f};
  f32x4 acc[4];
#pragma unroll
  for (int i = 0; i < 4; i++) acc[i] = zero;
#pragma unroll
  for (int kk = 0; kk < 4; kk++) {
    f16x8 bf[4];
#pragma unroll
    for (int nt = 0; nt < 4; nt++)
      bf[nt] = *(const f16x8*)(W1t + (size_t)(c * 64 + nt * 16 + mrow) * HID + kk * 32 + quad * 8);
#pragma unroll
    for (int nt = 0; nt < 4; nt++)
      acc[nt] = __builtin_amdgcn_mfma_f32_16x16x32_f16(af[kk], bf[nt], acc[nt], 0, 0, 0);
  }
#pragma unroll
  for (int nt = 0; nt < 4; nt++) {
    int colv = c * 64 + nt * 16 + mrow;
#pragma unroll
    for (int r = 0; r < 4; r++)
      Ys[(g * 16 + quad * 4 + r) * LDX + colv] = (_Float16)acc[nt][r];
  }
  __syncthreads();
#pragma unroll
  for (int p = 0; p < 2; p++) {
    int id = t + p * 256;          // 512 uint4 chunks (32 rows x 16)
    int a = id >> 4, kg = id & 15;
    if (a0 + a < N)
      ((uint4*)x16)[(size_t)(a0 + a) * 16 + kg] = *(uint4*)&Ys[a * LDX + kg * 8];
  }
}

// ---- mid layers: h' = h + ssp(agg@W2+b2)@W3+b3 (store h), x16 = h'@W1next
__global__ __launch_bounds__(256) void fused_mid_k(
    const _Float16* __restrict__ agg16, const _Float16* __restrict__ W2t,
    const float* __restrict__ b2, const _Float16* __restrict__ W3t,
    const float* __restrict__ b3, float* __restrict__ h,
    const _Float16* __restrict__ W1nt, _Float16* __restrict__ x16, int N) {
  __shared__ __align__(16) _Float16 Xs[32 * LDX];
  __shared__ __align__(16) _Float16 Ys[32 * LDX];
  int t = threadIdx.x;
  int lane = t & 63, w = t >> 6;
  int g = w & 1, c = w >> 1;
  int mrow = lane & 15, quad = lane >> 4;
  int a0 = blockIdx.x * 32;
#pragma unroll
  for (int p = 0; p < 2; p++) {
    int id = t + p * 256;
    int a = id >> 4, kg = id & 15;
    uint4 v = make_uint4(0, 0, 0, 0);
    if (a0 + a < N) v = ((const uint4*)agg16)[(size_t)(a0 + a) * 16 + kg];
    *(uint4*)&Xs[a * LDX + kg * 8] = v;
  }
  __syncthreads();
  f32x4 zero = {0.f, 0.f, 0.f, 0.f};
  f16x8 af[4];
  f32x4 acc[4];
  // GEMM1: ssp(agg @ W2 + b2) -> Ys
#pragma unroll
  for (int kk = 0; kk < 4; kk++)
    af[kk] = *(const f16x8*)&Xs[(g * 16 + mrow) * LDX + kk * 32 + quad * 8];
#pragma unroll
  for (int i = 0; i < 4; i++) acc[i] = zero;
#pragma unroll
  for (int kk = 0; kk < 4; kk++) {
    f16x8 bf[4];
#pragma unroll
    for (int nt = 0; nt < 4; nt++)
      bf[nt] = *(const f16x8*)(W2t + (size_t)(c * 64 + nt * 16 + mrow) * HID + kk * 32 + quad * 8);
#pragma unroll
    for (int nt = 0; nt < 4; nt++)
      acc[nt] = __builtin_amdgcn_mfma_f32_16x16x32_f16(af[kk], bf[nt], acc[nt], 0, 0, 0);
  }
#pragma unroll
  for (int nt = 0; nt < 4; nt++) {
    int colv = c * 64 + nt * 16 + mrow;
    float bb = b2[colv];
#pragma unroll
    for (int r = 0; r < 4; r++)
      Ys[(g * 16 + quad * 4 + r) * LDX + colv] = (_Float16)sspf(acc[nt][r] + bb);
  }
  __syncthreads();
  // GEMM2: (Ys @ W3 + b3) -> Xs
#pragma unroll
  for (int kk = 0; kk < 4; kk++)
    af[kk] = *(const f16x8*)&Ys[(g * 16 + mrow) * LDX + kk * 32 + quad * 8];
#pragma unroll
  for (int i = 0; i < 4; i++) acc[i] = zero;
#pragma unroll
  for (int kk = 0; kk < 4; kk++) {
    f16x8 bf[4];
#pragma unroll
    for (int nt = 0; nt < 4; nt++)
      bf[nt] = *(const f16x8*)(W3t + (size_t)(c * 64 + nt * 16 + mrow) * HID + kk * 32 + quad * 8);
#pragma unroll
    for (int nt = 0; nt < 4; nt++)
      acc[nt] = __builtin_amdgcn_mfma_f32_16x16x32_f16(af[kk], bf[nt], acc[nt], 0, 0, 0);
  }
#pragma unroll
  for (int nt = 0; nt < 4; nt++) {
    int colv = c * 64 + nt * 16 + mrow;
    float bb = b3[colv];
#pragma unroll
    for (int r = 0; r < 4; r++)
      Xs[(g * 16 + quad * 4 + r) * LDX + colv] = (_Float16)(acc[nt][r] + bb);
  }
  __syncthreads();
  // residual: h' = h + Xs (coalesced), Xs <- fp16(h')
#pragma unroll
  for (int p = 0; p < 4; p++) {
    int id = t + p * 256;
    int a = id >> 5, kg = id & 31;
    h4 xv = *(h4*)&Xs[a * LDX + kg * 4];
    float4 v = make_float4((float)xv.x, (float)xv.y, (float)xv.z, (float)xv.w);
    if (a0 + a < N) {
      float4 ho = ((const float4*)h)[(size_t)(a0 + a) * 32 + kg];
      v.x += ho.x; v.y += ho.y; v.z += ho.z; v.w += ho.w;
      ((float4*)h)[(size_t)(a0 + a) * 32 + kg] = v;
    }
    h4 o;
    o.x = (_Float16)v.x; o.y = (_Float16)v.y;
    o.z = (_Float16)v.z; o.w = (_Float16)v.w;
    *(h4*)&Xs[a * LDX + kg * 4] = o;
  }
  __syncthreads();
  // GEMM3: (Xs @ W1next) -> Ys
#pragma unroll
  for (int kk = 0; kk < 4; kk++)
    af[kk] = *(const f16x8*)&Xs[(g * 16 + mrow) * LDX + kk * 32 + quad * 8];
#pragma unroll
  for (int i = 0; i < 4; i++) acc[i] = zero;
#pragma unroll
  for (int kk = 0; kk < 4; kk++) {
    f16x8 bf[4];
#pragma unroll
    for (int nt = 0; nt < 4; nt++)
      bf[nt] = *(const f16x8*)(W1nt + (size_t)(c * 64 + nt * 16 + mrow) * HID + kk * 32 + quad * 8);
#pragma unroll
    for (int nt = 0; nt < 4; nt++)
      acc[nt] = __builtin_amdgcn_mfma_f32_16x16x32_f16(af[kk], bf[nt], acc[nt], 0, 0, 0);
  }
#pragma unroll
  for (int nt = 0; nt < 4; nt++) {
    int colv = c * 64 + nt * 16 + mrow;
#pragma unroll
    for (int r = 0; r < 4; r++)
      Ys[(g * 16 + quad * 4 + r) * LDX + colv] = (_Float16)acc[nt][r];
  }
  __syncthreads();
#pragma unroll
  for (int p = 0; p < 2; p++) {
    int id = t + p * 256;
    int a = id >> 4, kg = id & 15;
    if (a0 + a < N)
      ((uint4*)x16)[(size_t)(a0 + a) * 16 + kg] = *(uint4*)&Ys[a * LDX + kg * 8];
  }
}

// ---- last layer: h'=h+... -> ssp(h'@o1w+o1b).o2w -> atomic out[batch]
__global__ __launch_bounds__(256) void fused_last_k(
    const _Float16* __restrict__ agg16, const _Float16* __restrict__ W2t,
    const float* __restrict__ b2, const _Float16* __restrict__ W3t,
    const float* __restrict__ b3, const float* __restrict__ h,
    const _Float16* __restrict__ Wo1t, const float* __restrict__ o1b,
    const float* __restrict__ o2w, const float* __restrict__ o2b,
    const int* __restrict__ batch, float* __restrict__ out, int N) {
  __shared__ __align__(16) _Float16 Xs[32 * LDX];
  __shared__ __align__(16) _Float16 Ys[32 * LDX];
  __shared__ float ebuf[32];
  int t = threadIdx.x;
  int lane = t & 63, w = t >> 6;
  int g = w & 1, c = w >> 1;
  int mrow = lane & 15, quad = lane >> 4;
  int a0 = blockIdx.x * 32;
  if (t < 32) ebuf[t] = 0.f;
#pragma unroll
  for (int p = 0; p < 2; p++) {
    int id = t + p * 256;
    int a = id >> 4, kg = id & 15;
    uint4 v = make_uint4(0, 0, 0, 0);
    if (a0 + a < N) v = ((const uint4*)agg16)[(size_t)(a0 + a) * 16 + kg];
    *(uint4*)&Xs[a * LDX + kg * 8] = v;
  }
  __syncthreads();
  f32x4 zero = {0.f, 0.f, 0.f, 0.f};
  f16x8 af[4];
  f32x4 acc[4];
#pragma unroll
  for (int kk = 0; kk < 4; kk++)
    af[kk] = *(const f16x8*)&Xs[(g * 16 + mrow) * LDX + kk * 32 + quad * 8];
#pragma unroll
  for (int i = 0; i < 4; i++) acc[i] = zero;
#pragma unroll
  for (int kk = 0; kk < 4; kk++) {
    f16x8 bf[4];
#pragma unroll
    for (int nt = 0; nt < 4; nt++)
      bf[nt] = *(const f16x8*)(W2t + (size_t)(c * 64 + nt * 16 + mrow) * HID + kk * 32 + quad * 8);
#pragma unroll
    for (int nt = 0; nt < 4; nt++)
      acc[nt] = __builtin_amdgcn_mfma_f32_16x16x32_f16(af[kk], bf[nt], acc[nt], 0, 0, 0);
  }
#pragma unroll
  for (int nt = 0; nt < 4; nt++) {
    int colv = c * 64 + nt * 16 + mrow;
    float bb = b2[colv];
#pragma unroll
    for (int r = 0; r < 4; r++)
      Ys[(g * 16 + quad * 4 + r) * LDX + colv] = (_Float16)sspf(acc[nt][r] + bb);
  }
  __syncthreads();
#pragma unroll
  for (int kk = 0; kk < 4; kk++)
    af[kk] = *(const f16x8*)&Ys[(g * 16 + mrow) * LDX + kk * 32 + quad * 8];
#pragma unroll
  for (int i = 0; i < 4; i++) acc[i] = zero;
#pragma unroll
  for (int kk = 0; kk < 4; kk++) {
    f16x8 bf[4];
#pragma unroll
    for (int nt = 0; nt < 4; nt++)
      bf[nt] = *(const f16x8*)(W3t + (size_t)(c * 64 + nt * 16 + mrow) * HID + kk * 32 + quad * 8);
#pragma unroll
    for (int nt = 0; nt < 4; nt++)
      acc[nt] = __builtin_amdgcn_mfma_f32_16x16x32_f16(af[kk], bf[nt], acc[nt], 0, 0, 0);
  }
#pragma unroll
  for (int nt = 0; nt < 4; nt++) {
    int colv = c * 64 + nt * 16 + mrow;
    float bb = b3[colv];
#pragma unroll
    for (int r = 0; r < 4; r++)
      Xs[(g * 16 + quad * 4 + r) * LDX + colv] = (_Float16)(acc[nt][r] + bb);
  }
  __syncthreads();
  // h' = h + Xs (h read-only)
#pragma unroll
  for (int p = 0; p < 4; p++) {
    int id = t + p * 256;
    int a = id >> 5, kg = id & 31;
    h4 xv = *(h4*)&Xs[a * LDX + kg * 4];
    float4 v = make_float4((float)xv.x, (float)xv.y, (float)xv.z, (float)xv.w);
    if (a0 + a < N) {
      float4 ho = ((const float4*)h)[(size_t)(a0 + a) * 32 + kg];
      v.x += ho.x; v.y += ho.y; v.z += ho.z; v.w += ho.w;
    }
    h4 o;
    o.x = (_Float16)v.x; o.y = (_Float16)v.y;
    o.z = (_Float16)v.z; o.w = (_Float16)v.w;
    *(h4*)&Xs[a * LDX + kg * 4] = o;
  }
  __syncthreads();
  // GEMM3: h' @ o1w (64 cols; col-split 32 per wave) -> energy dot + reduce
#pragma unroll
  for (int kk = 0; kk < 4; kk++)
    af[kk] = *(const f16x8*)&Xs[(g * 16 + mrow) * LDX + kk * 32 + quad * 8];
#pragma unroll
  for (int i = 0; i < 2; i++) acc[i] = zero;
#pragma unroll
  for (int kk = 0; kk < 4; kk++) {
    f16x8 bf[2];
#pragma unroll
    for (int nt = 0; nt < 2; nt++)
      bf[nt] = *(const f16x8*)(Wo1t + (size_t)(c * 32 + nt * 16 + mrow) * HID + kk * 32 + quad * 8);
#pragma unroll
    for (int nt = 0; nt < 2; nt++)
      acc[nt] = __builtin_amdgcn_mfma_f32_16x16x32_f16(af[kk], bf[nt], acc[nt], 0, 0, 0);
  }
  float ss[4] = {0.f, 0.f, 0.f, 0.f};
#pragma unroll
  for (int nt = 0; nt < 2; nt++) {
    int colv = c * 32 + nt * 16 + mrow;
    float bb = o1b[colv];
    float ww = o2w[colv];
#pragma unroll
    for (int r = 0; r < 4; r++) ss[r] += sspf(acc[nt][r] + bb) * ww;
  }
#pragma unroll
  for (int r = 0; r < 4; r++) {
    ss[r] += __shfl_xor(ss[r], 1);
    ss[r] += __shfl_xor(ss[r], 2);
    ss[r] += __shfl_xor(ss[r], 4);
    ss[r] += __shfl_xor(ss[r], 8);
    if (mrow == 0) atomicAdd(&ebuf[g * 16 + quad * 4 + r], ss[r]);
  }
  __syncthreads();
  if (t < 32) {
    int a = a0 + t;
    if (a < N) atomicAdd(&out[batch[a]], ebuf[t] + o2b[0]);
  }
}

// ---- agg16[a] = (fp16) sum_{e: col=a} x16[row_e] * tabh[tq_e]
__global__ __launch_bounds__(256) void aggregate_k(
    const int* __restrict__ starts, const unsigned int* __restrict__ payload,
    const _Float16* __restrict__ x16, const _Float16* __restrict__ tabh,
    _Float16* __restrict__ agg16, int N) {
  int a = blockIdx.x * 4 + (threadIdx.x >> 6);
  if (a >= N) return;
  int lane = threadIdx.x & 63;
  int half = lane >> 5;
  int sl = lane & 31;
  int s = starts[a], e_end = starts[a + 1];
  float4 acc0 = make_float4(0.f, 0.f, 0.f, 0.f);
  float4 acc1 = make_float4(0.f, 0.f, 0.f, 0.f);
  auto do_edge = [&](unsigned int p, float4& acc) {
    int tq = (int)(p & 8191u);
    int r = (int)(p >> 13);
    h4 tw = *(const h4*)&tabh[(size_t)tq * HID + sl * 4];
    h4 xr = *(const h4*)&x16[(size_t)r * HID + sl * 4];
    acc.x = fmaf((float)xr.x, (float)tw.x, acc.x);
    acc.y = fmaf((float)xr.y, (float)tw.y, acc.y);
    acc.z = fmaf((float)xr.z, (float)tw.z, acc.z);
    acc.w = fmaf((float)xr.w, (float)tw.w, acc.w);
  };
  int i = s;
  for (; i + 8 <= e_end; i += 8) {
    unsigned int p0 = payload[i + half];
    unsigned int p1 = payload[i + 2 + half];
    unsigned int p2 = payload[i + 4 + half];
    unsigned int p3 = payload[i + 6 + half];
    do_edge(p0, acc0);
    do_edge(p1, acc1);
    do_edge(p2, acc0);
    do_edge(p3, acc1);
  }
  for (; i < e_end; i += 2) {
    int e = i + half;
    if (e < e_end) do_edge(payload[e], acc0);
  }
  acc0.x += acc1.x; acc0.y += acc1.y; acc0.z += acc1.z; acc0.w += acc1.w;
  acc0.x += __shfl_xor(acc0.x, 32);
  acc0.y += __shfl_xor(acc0.y, 32);
  acc0.z += __shfl_xor(acc0.z, 32);
  acc0.w += __shfl_xor(acc0.w, 32);
  if (half == 0) {
    h4 o;
    o.x = (_Float16)acc0.x; o.y = (_Float16)acc0.y;
    o.z = (_Float16)acc0.z; o.w = (_Float16)acc0.w;
    *(h4*)&agg16[(size_t)a * HID + sl * 4] = o;
  }
}

extern "C" void kernel_launch(void* const* d_in, const int* in_sizes, int n_in,
                              void* d_out, int out_size, void* d_ws, size_t ws_size,
                              hipStream_t stream) {
  const int* z = (const int*)d_in[0];
  const float* pos = (const float*)d_in[1];
  const int* batch = (const int*)d_in[2];
  const int* eidx = (const int*)d_in[3];
  const float* emb = (const float*)d_in[4];
  const float* mlp1_w = (const float*)d_in[5];
  const float* mlp1_b = (const float*)d_in[6];
  const float* mlp2_w = (const float*)d_in[7];
  const float* mlp2_b = (const float*)d_in[8];
  const float* lin1_w = (const float*)d_in[9];
  const float* lin2_w = (const float*)d_in[10];
  const float* lin2_b = (const float*)d_in[11];
  const float* int_w = (const float*)d_in[12];
  const float* int_b = (const float*)d_in[13];
  const float* out1_w = (const float*)d_in[14];
  const float* out1_b = (const float*)d_in[15];
  const float* out2_w = (const float*)d_in[16];
  const float* out2_b = (const float*)d_in[17];
  float* out = (float*)d_out;

  const int N = in_sizes[0];
  const int E = in_sizes[3] / 2;
  const int* row = eidx;
  const int* col = eidx + E;
  const int nbuck = (N + 63) / 64;

  char* ws = (char*)d_ws;
  size_t off = 0;
  auto alloc = [&](size_t bytes) -> void* {
    void* p = ws + off;
    off = (off + bytes + 255) & ~(size_t)255;
    return p;
  };
  float* h = (float*)alloc((size_t)N * HID * 4);
  _Float16* x16 = (_Float16*)alloc((size_t)N * HID * 2);
  size_t agg_bytes = (size_t)N * HID * 2;
  size_t tmp_bytes = (size_t)E * 8 + 16;
  void* agg_union = alloc(agg_bytes > tmp_bytes ? agg_bytes : tmp_bytes);
  _Float16* agg16 = (_Float16*)agg_union;
  unsigned long long* tmp = (unsigned long long*)agg_union;
  unsigned int* payload = (unsigned int*)alloc((size_t)E * 4 + 16);
  int* starts = (int*)alloc((size_t)(N + 1) * 4);
  int* bcount = (int*)alloc((size_t)nbuck * 4);
  int* bstart = (int*)alloc((size_t)(nbuck + 1) * 4);
  int* bcur = (int*)alloc((size_t)nbuck * 4);
  float* tab = (float*)alloc((size_t)3 * TBL * HID * 4);
  _Float16* tabh = (_Float16*)alloc((size_t)3 * TBL2 * HID * 2);
  _Float16* Wt10 = (_Float16*)alloc((size_t)10 * HID * HID * 2);
  (void)ws_size;

  hipMemsetAsync(bcount, 0, (size_t)nbuck * 4, stream);
  hipMemsetAsync(out, 0, (size_t)out_size * 4, stream);

  build_table_k<<<3 * TBL, 128, 0, stream>>>(mlp1_w, mlp1_b, mlp2_w, mlp2_b, tab);
  upsample_k<<<(3 * TBL2 * HID + 255) / 256, 256, 0, stream>>>(tab, tabh);
  wtrans10_k<<<10, 256, 0, stream>>>(lin1_w, lin2_w, int_w, out1_w, Wt10);
  bcount_k<<<(E + 2047) / 2048, 256, 0, stream>>>(col, bcount, E, nbuck);
  bucket_scan_k<<<1, 256, 0, stream>>>(bcount, bstart, bcur, nbuck, starts, N);
  scatterA_k<<<(E + 2047) / 2048, 256, 0, stream>>>(row, col, pos, bcur, tmp, E, nbuck);
  scatterB_k<<<nbuck, 256, 0, stream>>>(tmp, bstart, starts, payload, N);

  int g32 = (N + 31) / 32;
  lin1_emb_k<<<g32, 256, 0, stream>>>(z, emb, Wt10, h, x16, N);
  for (int l = 0; l < 2; l++) {
    aggregate_k<<<(N + 3) / 4, 256, 0, stream>>>(starts, payload, x16,
                                                 tabh + (size_t)l * TBL2 * HID, agg16, N);
    fused_mid_k<<<g32, 256, 0, stream>>>(
        agg16, Wt10 + (size_t)(3 + l) * HID * HID, lin2_b + (size_t)l * HID,
        Wt10 + (size_t)(6 + l) * HID * HID, int_b + (size_t)l * HID, h,
        Wt10 + (size_t)(l + 1) * HID * HID, x16, N);
  }
  aggregate_k<<<(N + 3) / 4, 256, 0, stream>>>(starts, payload, x16,
                                               tabh + (size_t)2 * TBL2 * HID, agg16, N);
  fused_last_k<<<g32, 256, 0, stream>>>(
      agg16, Wt10 + (size_t)5 * HID * HID, lin2_b + (size_t)2 * HID,
      Wt10 + (size_t)8 * HID * HID, int_b + (size_t)2 * HID, h,
      Wt10 + (size_t)9 * HID * HID, out1_b, out2_w, out2_b, batch, out, N);
}